// Round 7
// baseline (1054.515 us; speedup 1.0000x reference)
//
#include <hip/hip_runtime.h>

// ---------- types ----------
typedef __bf16 bf16;
typedef __attribute__((ext_vector_type(8))) __bf16 bf16x8;
typedef __attribute__((ext_vector_type(4))) float f32x4;

#define T_SEQ 1024
#define D_MODEL 512
#define N_INT 2048
#define NHEADS 8
#define IN_DIM 372
#define IN_PAD 384
#define OUT_DIM 186
#define OUT_PAD 256

__device__ inline void gld16(const bf16* g, bf16* l) {
  __builtin_amdgcn_global_load_lds((const __attribute__((address_space(1))) void*)g,
                                   (__attribute__((address_space(3))) void*)l, 16, 0, 0);
}

// block-wide sum of two values (256 threads)
__device__ inline void block_sum2(float& a, float& b, float* red) {
#pragma unroll
  for (int o = 32; o > 0; o >>= 1) {
    a += __shfl_down(a, o, 64);
    b += __shfl_down(b, o, 64);
  }
  __syncthreads();
  if ((threadIdx.x & 63) == 0) {
    int w = threadIdx.x >> 6;
    red[2 * w] = a;
    red[2 * w + 1] = b;
  }
  __syncthreads();
  a = red[0] + red[2] + red[4] + red[6];
  b = red[1] + red[3] + red[5] + red[7];
}

// ---------- transpose + fp32->bf16 convert ----------
__global__ __launch_bounds__(256) void transpose_cvt(const float* __restrict__ in,
                                                     bf16* __restrict__ out,
                                                     int rows, int cols) {
  __shared__ float tile[32][33];
  size_t zoff = (size_t)blockIdx.z * rows * cols;
  in += zoff;
  out += zoff;
  int c0 = blockIdx.x * 32, r0 = blockIdx.y * 32;
#pragma unroll
  for (int i = threadIdx.y; i < 32; i += 8)
    tile[i][threadIdx.x] = in[(size_t)(r0 + i) * cols + c0 + threadIdx.x];
  __syncthreads();
#pragma unroll
  for (int i = threadIdx.y; i < 32; i += 8)
    out[(size_t)(c0 + i) * rows + r0 + threadIdx.x] = (bf16)tile[threadIdx.x][i];
}

// ---------- zero-padded transpose + cvt ----------
__global__ __launch_bounds__(256) void pad_trans(const float* __restrict__ in,
                                                 bf16* __restrict__ out,
                                                 int R, int C, int outLd) {
  __shared__ float tile[32][33];
  int c0 = blockIdx.x * 32, r0 = blockIdx.y * 32;
#pragma unroll
  for (int i = threadIdx.y; i < 32; i += 8) {
    int r = r0 + i, c = c0 + threadIdx.x;
    tile[i][threadIdx.x] = (r < R && c < C) ? in[(size_t)r * C + c] : 0.f;
  }
  __syncthreads();
#pragma unroll
  for (int i = threadIdx.y; i < 32; i += 8)
    out[(size_t)(c0 + i) * outLd + r0 + threadIdx.x] = (bf16)tile[threadIdx.x][i];
}

// ---------- x fp32 [2048][372] -> xbf bf16 [2048][384] zero-padded ----------
__global__ __launch_bounds__(256) void cvt_pad_x(const float* __restrict__ x,
                                                 bf16* __restrict__ xbf) {
  size_t r = blockIdx.x;
  for (int c = threadIdx.x; c < IN_PAD; c += 256)
    xbf[r * IN_PAD + c] = (c < IN_DIM) ? (bf16)x[r * IN_DIM + c] : (bf16)0.f;
}

// ---------- RoPE tables ----------
__global__ __launch_bounds__(256) void rope_tables(float* __restrict__ ct, float* __restrict__ st) {
  int t = blockIdx.x;
  for (int i = threadIdx.x; i < 1024; i += 256) {
    float ph = (float)t * exp2f(-16.0f * (float)i * (1.0f / 1024.0f));
    ct[(size_t)t * 1024 + i] = cosf(ph);
    st[(size_t)t * 1024 + i] = sinf(ph);
  }
}

// ---------- sum 16 bf16 split-K partials -> fp32 zbuf (per batch) ----------
__global__ __launch_bounds__(256) void psum16(const bf16* __restrict__ part,
                                              float* __restrict__ zb) {
  size_t r = blockIdx.x;  // 1024 rows
  for (int cc = threadIdx.x; cc < 512; cc += 256) {
    float s = 0.f;
#pragma unroll
    for (int k = 0; k < 16; ++k)
      s += (float)part[((size_t)k << 19) + r * 512 + cc];
    zb[r * 512 + cc] = s;
  }
}

// ---------- ln0: h = LN(z) ----------
__global__ __launch_bounds__(256) void ln0(const float* __restrict__ zin,
                                           float* __restrict__ h, bf16* __restrict__ hbf,
                                           bf16* __restrict__ hT) {
  __shared__ float red[8];
  size_t r = blockIdx.x;
  int tid = threadIdx.x;
  float v0 = zin[r * 512 + tid], v1 = zin[r * 512 + tid + 256];
  float s = v0 + v1, s2 = v0 * v0 + v1 * v1;
  block_sum2(s, s2, red);
  float mean = s * (1.f / 512.f);
  float var = s2 * (1.f / 512.f) - mean * mean;
  float rs = rsqrtf(var + 1e-5f);
  float o0 = (v0 - mean) * rs, o1 = (v1 - mean) * rs;
  h[r * 512 + tid] = o0;
  h[r * 512 + tid + 256] = o1;
  hbf[r * 512 + tid] = (bf16)o0;
  hbf[r * 512 + tid + 256] = (bf16)o1;
  int b = (int)(r >> 10), t = (int)(r & (T_SEQ - 1));
  hT[((size_t)b * 512 + tid) * T_SEQ + t] = (bf16)o0;
  hT[((size_t)b * 512 + tid + 256) * T_SEQ + t] = (bf16)o1;
}

// ---------- in-place LN on bf16 rows of 512 ----------
__global__ __launch_bounds__(256) void ln_rows(bf16* __restrict__ io) {
  __shared__ float red[8];
  size_t r = blockIdx.x;
  int tid = threadIdx.x;
  float v0 = (float)io[r * 512 + tid], v1 = (float)io[r * 512 + tid + 256];
  float s = v0 + v1, s2 = v0 * v0 + v1 * v1;
  block_sum2(s, s2, red);
  float mean = s * (1.f / 512.f);
  float var = s2 * (1.f / 512.f) - mean * mean;
  float rs = rsqrtf(var + 1e-5f);
  io[r * 512 + tid] = (bf16)((v0 - mean) * rs);
  io[r * 512 + tid + 256] = (bf16)((v1 - mean) * rs);
}

// ---------- h = LN(h_res + LN(z)) ----------
__global__ __launch_bounds__(256) void ln_double(const float* __restrict__ zin,
                                                 float* __restrict__ h, bf16* __restrict__ hbf,
                                                 bf16* __restrict__ hT) {
  __shared__ float red[8];
  size_t r = blockIdx.x;
  int tid = threadIdx.x;
  float z0 = zin[r * 512 + tid], z1 = zin[r * 512 + tid + 256];
  float s = z0 + z1, s2 = z0 * z0 + z1 * z1;
  block_sum2(s, s2, red);
  float m1 = s * (1.f / 512.f);
  float v1_ = s2 * (1.f / 512.f) - m1 * m1;
  float rs1 = rsqrtf(v1_ + 1e-5f);
  float a0 = (z0 - m1) * rs1 + h[r * 512 + tid];
  float a1 = (z1 - m1) * rs1 + h[r * 512 + tid + 256];
  s = a0 + a1;
  s2 = a0 * a0 + a1 * a1;
  block_sum2(s, s2, red);
  float m2 = s * (1.f / 512.f);
  float v2_ = s2 * (1.f / 512.f) - m2 * m2;
  float rs2 = rsqrtf(v2_ + 1e-5f);
  float o0 = (a0 - m2) * rs2, o1 = (a1 - m2) * rs2;
  h[r * 512 + tid] = o0;
  h[r * 512 + tid + 256] = o1;
  hbf[r * 512 + tid] = (bf16)o0;
  hbf[r * 512 + tid + 256] = (bf16)o1;
  int b = (int)(r >> 10), t = (int)(r & (T_SEQ - 1));
  hT[((size_t)b * 512 + tid) * T_SEQ + t] = (bf16)o0;
  hT[((size_t)b * 512 + tid + 256) * T_SEQ + t] = (bf16)o1;
}

// ---------- fused hsp+RoPE GEMM: per block, M-tile 128 x N-pair (c, c+1024) of 64 ----------
// hsp = relu(hbf_b @ encT^T); qr = RoPE(hsp).  A staged once for both B panels.
__global__ __launch_bounds__(256, 2) void g_hspr(const bf16* __restrict__ hbf_b,
                                                 const bf16* __restrict__ encT,
                                                 const float* __restrict__ ct,
                                                 const float* __restrict__ st,
                                                 bf16* __restrict__ hsp,
                                                 bf16* __restrict__ qr) {
  const int id = blockIdx.x;
  const int bz = id & 7;
  const int r_ = id >> 3;
  const int bi = r_ & 7;   // 8 M-tiles of 128
  const int bj = r_ >> 3;  // 16 N-pair tiles of 64

  const bf16* B0 = encT + (size_t)bz * N_INT * 512 + (size_t)(bj * 64) * 512;
  const bf16* B1 = B0 + (size_t)1024 * 512;

  const int tid = threadIdx.x;
  const int trow = tid >> 3, tq = tid & 7;
  const int sq = tq ^ (trow & 7);
  const bf16* ags = hbf_b + (size_t)(bi * 128 + trow) * 512 + sq * 8;
  const bf16* bgs0 = B0 + (size_t)trow * 512 + sq * 8;
  const bf16* bgs1 = B1 + (size_t)trow * 512 + sq * 8;

  __shared__ __align__(16) bf16 As[2][128 * 64];
  __shared__ __align__(16) bf16 Bs[2][2 * 64 * 64];
  const int so = tid * 8;

  const int lane = tid & 63, wid = tid >> 6;
  const int wr = wid >> 1, wc = wid & 1;
  const int fr = lane & 15, fg = lane >> 4;
  const int axor = fr & 7;

  f32x4 acc[4][2][2] = {};

  auto stage = [&](int buf, int kk) {
#pragma unroll
    for (int p = 0; p < 4; ++p)
      gld16(ags + (size_t)(p * 32) * 512 + kk, &As[buf][p * 2048 + so]);
    gld16(bgs0 + kk, &Bs[buf][0 * 2048 + so]);
    gld16(bgs0 + (size_t)32 * 512 + kk, &Bs[buf][1 * 2048 + so]);
    gld16(bgs1 + kk, &Bs[buf][2 * 2048 + so]);
    gld16(bgs1 + (size_t)32 * 512 + kk, &Bs[buf][3 * 2048 + so]);
  };

  stage(0, 0);
  for (int t = 0; t < 8; ++t) {
    const int cur = t & 1;
    if (t + 1 < 8) {
      stage(cur ^ 1, (t + 1) << 6);
      asm volatile("s_waitcnt vmcnt(8)" ::: "memory");
    } else {
      asm volatile("s_waitcnt vmcnt(0)" ::: "memory");
    }
    __builtin_amdgcn_sched_barrier(0);
    __builtin_amdgcn_s_barrier();
    __builtin_amdgcn_sched_barrier(0);

    __builtin_amdgcn_s_setprio(1);
#pragma unroll
    for (int s = 0; s < 2; ++s) {
      bf16x8 af[4], bfv[2][2];
#pragma unroll
      for (int m = 0; m < 4; ++m)
        af[m] = *(const bf16x8*)(&As[cur][(wr * 64 + m * 16 + fr) * 64 + (((s * 4 + fg) ^ axor) * 8)]);
#pragma unroll
      for (int pp = 0; pp < 2; ++pp)
#pragma unroll
        for (int n = 0; n < 2; ++n)
          bfv[pp][n] = *(const bf16x8*)(&Bs[cur][pp * 4096 + (wc * 32 + n * 16 + fr) * 64 + (((s * 4 + fg) ^ axor) * 8)]);
#pragma unroll
      for (int m = 0; m < 4; ++m)
#pragma unroll
        for (int n = 0; n < 2; ++n)
#pragma unroll
          for (int pp = 0; pp < 2; ++pp)
            acc[m][n][pp] = __builtin_amdgcn_mfma_f32_16x16x32_bf16(af[m], bfv[pp][n], acc[m][n][pp], 0, 0, 0);
    }
    __builtin_amdgcn_s_setprio(0);

    asm volatile("s_waitcnt lgkmcnt(0)" ::: "memory");
    __builtin_amdgcn_sched_barrier(0);
    __builtin_amdgcn_s_barrier();
    __builtin_amdgcn_sched_barrier(0);
  }

  const size_t hb = (size_t)bz * T_SEQ;
#pragma unroll
  for (int m = 0; m < 4; ++m) {
#pragma unroll
    for (int n = 0; n < 2; ++n) {
      int c = bj * 64 + wc * 32 + n * 16 + fr;
#pragma unroll
      for (int j = 0; j < 4; ++j) {
        int r = bi * 128 + wr * 64 + m * 16 + fg * 4 + j;
        float v0 = fmaxf(acc[m][n][0][j], 0.f);
        float v1 = fmaxf(acc[m][n][1][j], 0.f);
        float co = ct[(size_t)r * 1024 + c];
        float si = st[(size_t)r * 1024 + c];
        size_t base = (hb + r) * N_INT + c;
        hsp[base] = (bf16)v0;
        hsp[base + 1024] = (bf16)v1;
        qr[base] = (bf16)(v0 * co - v1 * si);
        qr[base + 1024] = (bf16)(v1 * co + v0 * si);
      }
    }
  }
}

// ---------- TILE x TILE bf16 MFMA GEMM body, C = A @ Bt^T ----------
// BK=64, DEPTH-deep prefetch (DEPTH+1 LDS buffers), counted vmcnt (T4),
// XOR-swizzle (T2, pre-swizzled global source), XCD pin (T1).
// MODE 1: S   = causal(qr @ qr^T)            TILE=64, DEPTH=2
// MODE 2: ykv = bf16(S @ hT_b^T)             TILE=64, DEPTH=2, K causal-bounded
// MODE 3: xy  = relu(ykv @ encvT^T) * hsp    TILE=128
// MODE 4: part[chunk] = bf16(xy @ decT^T)    TILE=128, split-K-16
// MODE 5: zbuf = xbf @ WiT^T + bi            TILE=128
// MODE 6: out  = hbf @ WoT^T + bo            TILE=128, masked c<186
template <int MODE, int GX, int TILE, int DEPTH>
__device__ __forceinline__ void gemm_body(const bf16* __restrict__ Abase,
                                          const bf16* __restrict__ Bbase,
                                          const bf16* __restrict__ aux,
                                          const float* __restrict__ fbias,
                                          float* __restrict__ fout,
                                          bf16* __restrict__ bout) {
  const int id = blockIdx.x;
  int bz = 0, r_, chunk = 0;
  if constexpr (MODE >= 5) {
    r_ = id;
  } else if constexpr (MODE == 4) {
    r_ = id & 31;
    chunk = id >> 5;
  } else {
    bz = id & 7;
    r_ = id >> 3;
  }
  int bi, bj;
  if constexpr (MODE == 1) {
    int l = r_;
    float f = sqrtf(8.0f * (float)l + 1.0f);
    bi = (int)((f - 1.0f) * 0.5f);
    while ((bi + 1) * (bi + 2) / 2 <= l) ++bi;
    while (bi * (bi + 1) / 2 > l) --bi;
    bj = l - bi * (bi + 1) / 2;
  } else {
    bi = r_ % GX;
    bj = r_ / GX;
  }

  const bf16* A;
  const bf16* Bt;
  int lda, ldb, kend;
  if constexpr (MODE == 1) {
    A = Abase + (size_t)bz * T_SEQ * N_INT; lda = N_INT;
    Bt = A; ldb = N_INT;
    kend = N_INT;
  } else if constexpr (MODE == 2) {
    A = Abase + (size_t)bz * T_SEQ * T_SEQ; lda = T_SEQ;
    Bt = Bbase; ldb = T_SEQ;
    kend = (bi + 1) * TILE;
  } else if constexpr (MODE == 3) {
    A = Abase + (size_t)bz * T_SEQ * 512; lda = 512;
    Bt = Bbase + (size_t)bz * N_INT * 512; ldb = 512;
    kend = 512;
  } else if constexpr (MODE == 4) {
    A = Abase + (size_t)chunk * 1024; lda = 16384;
    Bt = Bbase + (size_t)chunk * 1024; ldb = 16384;
    kend = 1024;
  } else if constexpr (MODE == 5) {
    A = Abase; lda = IN_PAD;
    Bt = Bbase; ldb = IN_PAD;
    kend = IN_PAD;
  } else {
    A = Abase; lda = 512;
    Bt = Bbase; ldb = 512;
    kend = 512;
  }

  const int tid = threadIdx.x;
  constexpr int PASSES = TILE / 32;
  constexpr int NBUF = DEPTH + 1;
  const int trow = tid >> 3, tq = tid & 7;
  const int sq = tq ^ (trow & 7);
  const bf16* ags = A + (size_t)(bi * TILE + trow) * lda + sq * 8;
  const bf16* bgs = Bt + (size_t)(bj * TILE + trow) * ldb + sq * 8;

  __shared__ __align__(16) bf16 As[NBUF][TILE * 64];
  __shared__ __align__(16) bf16 Bs[NBUF][TILE * 64];
  const int so = tid * 8;

  const int lane = tid & 63, wid = tid >> 6;
  const int wr = wid >> 1, wc = wid & 1;
  const int fr = lane & 15, fg = lane >> 4;
  const int axor = fr & 7;
  constexpr int MR = TILE / 32;

  f32x4 acc[MR][MR] = {};

  auto stage = [&](int buf, int kk) {
#pragma unroll
    for (int p = 0; p < PASSES; ++p) {
      gld16(ags + (size_t)(p * 32) * lda + kk, &As[buf][p * 2048 + so]);
      gld16(bgs + (size_t)(p * 32) * ldb + kk, &Bs[buf][p * 2048 + so]);
    }
  };

  const int nt = kend >> 6;
  stage(0, 0);
  if constexpr (DEPTH == 2) {
    if (nt > 1) stage(1, 64);
  }

  for (int t = 0; t < nt; ++t) {
    const int cur = (DEPTH == 2) ? (t % 3) : (t & 1);
    if constexpr (DEPTH == 2) {
      if (t + 2 < nt) {
        stage((t + 2) % 3, (t + 2) << 6);
        if constexpr (TILE == 64) asm volatile("s_waitcnt vmcnt(8)" ::: "memory");
        else asm volatile("s_waitcnt vmcnt(16)" ::: "memory");
      } else if (t + 1 < nt) {
        if constexpr (TILE == 64) asm volatile("s_waitcnt vmcnt(4)" ::: "memory");
        else asm volatile("s_waitcnt vmcnt(8)" ::: "memory");
      } else {
        asm volatile("s_waitcnt vmcnt(0)" ::: "memory");
      }
    } else {
      if (t + 1 < nt) {
        stage(cur ^ 1, (t + 1) << 6);
        if constexpr (TILE == 64) asm volatile("s_waitcnt vmcnt(4)" ::: "memory");
        else asm volatile("s_waitcnt vmcnt(8)" ::: "memory");
      } else {
        asm volatile("s_waitcnt vmcnt(0)" ::: "memory");
      }
    }
    __builtin_amdgcn_sched_barrier(0);
    __builtin_amdgcn_s_barrier();
    __builtin_amdgcn_sched_barrier(0);

    __builtin_amdgcn_s_setprio(1);
#pragma unroll
    for (int s = 0; s < 2; ++s) {
      bf16x8 af[MR], bfv[MR];
#pragma unroll
      for (int m = 0; m < MR; ++m)
        af[m] = *(const bf16x8*)(&As[cur][(wr * (TILE / 2) + m * 16 + fr) * 64 + (((s * 4 + fg) ^ axor) * 8)]);
#pragma unroll
      for (int n = 0; n < MR; ++n)
        bfv[n] = *(const bf16x8*)(&Bs[cur][(wc * (TILE / 2) + n * 16 + fr) * 64 + (((s * 4 + fg) ^ axor) * 8)]);
#pragma unroll
      for (int m = 0; m < MR; ++m)
#pragma unroll
        for (int n = 0; n < MR; ++n)
          acc[m][n] = __builtin_amdgcn_mfma_f32_16x16x32_bf16(af[m], bfv[n], acc[m][n], 0, 0, 0);
    }
    __builtin_amdgcn_s_setprio(0);

    asm volatile("s_waitcnt lgkmcnt(0)" ::: "memory");
    __builtin_amdgcn_sched_barrier(0);
    __builtin_amdgcn_s_barrier();
    __builtin_amdgcn_sched_barrier(0);
  }

#pragma unroll
  for (int m = 0; m < MR; ++m) {
#pragma unroll
    for (int n = 0; n < MR; ++n) {
#pragma unroll
      for (int j = 0; j < 4; ++j) {
        int r = bi * TILE + wr * (TILE / 2) + m * 16 + fg * 4 + j;
        int c = bj * TILE + wc * (TILE / 2) + n * 16 + fr;
        float v = acc[m][n][j];
        if constexpr (MODE == 1) {
          bout[(size_t)bz * T_SEQ * T_SEQ + (size_t)r * T_SEQ + c] = (bf16)(c < r ? v : 0.f);
        } else if constexpr (MODE == 2) {
          bout[((size_t)bz * T_SEQ + r) * 512 + c] = (bf16)v;
        } else if constexpr (MODE == 3) {
          v = fmaxf(v, 0.f);
          float g = (float)aux[((size_t)bz * T_SEQ + r) * N_INT + c];
          bout[(size_t)r * 16384 + (size_t)bz * N_INT + c] = (bf16)(v * g);
        } else if constexpr (MODE == 4) {
          bout[((size_t)chunk << 19) + (size_t)r * 512 + c] = (bf16)v;
        } else if constexpr (MODE == 5) {
          fout[(size_t)r * 512 + c] = v + fbias[c];
        } else {
          if (c < OUT_DIM) fout[(size_t)r * OUT_DIM + c] = v + fbias[c];
        }
      }
    }
  }
}

// ---------- named wrappers ----------
__global__ __launch_bounds__(256, 3) void g_scores(const bf16* A, bf16* o) {
  gemm_body<1, 0, 64, 2>(A, nullptr, nullptr, nullptr, nullptr, o);
}
__global__ __launch_bounds__(256, 3) void g_pv(const bf16* A, const bf16* B, bf16* o) {
  gemm_body<2, 16, 64, 2>(A, B, nullptr, nullptr, nullptr, o);
}
__global__ __launch_bounds__(256, 2) void g_gate(const bf16* A, const bf16* B, const bf16* aux, bf16* o) {
  gemm_body<3, 8, 128, 1>(A, B, aux, nullptr, nullptr, o);
}
__global__ __launch_bounds__(256, 2) void g_dec(const bf16* A, const bf16* B, bf16* o) {
  gemm_body<4, 8, 128, 1>(A, B, nullptr, nullptr, nullptr, o);
}
__global__ __launch_bounds__(256, 2) void g_in(const bf16* A, const bf16* B, const float* bias, float* o) {
  gemm_body<5, 16, 128, 1>(A, B, nullptr, bias, o, nullptr);
}
__global__ __launch_bounds__(256, 2) void g_out(const bf16* A, const bf16* B, const float* bias, float* o) {
  gemm_body<6, 16, 128, 1>(A, B, nullptr, bias, o, nullptr);
}

// ---------- launch ----------
extern "C" void kernel_launch(void* const* d_in, const int* in_sizes, int n_in,
                              void* d_out, int out_size, void* d_ws, size_t ws_size,
                              hipStream_t stream) {
  const float* x = (const float*)d_in[0];
  const float* Wi = (const float*)d_in[1];
  const float* bi = (const float*)d_in[2];
  const float* enc = (const float*)d_in[3];
  const float* encv = (const float*)d_in[4];
  const float* dec = (const float*)d_in[5];
  const float* Wo = (const float*)d_in[6];
  const float* bo = (const float*)d_in[7];
  float* out = (float*)d_out;

  const size_t NEED = 163840000;
  if (ws_size < NEED) return;

  char* w = (char*)d_ws;
  auto alloc = [&](size_t bytes) {
    char* p = w;
    w += (bytes + 255) & ~(size_t)255;
    return p;
  };
  bf16* encT = (bf16*)alloc((size_t)NHEADS * N_INT * 512 * 2);
  bf16* encvT = (bf16*)alloc((size_t)NHEADS * N_INT * 512 * 2);
  bf16* decT = (bf16*)alloc((size_t)512 * 16384 * 2);
  float* cost = (float*)alloc((size_t)T_SEQ * 1024 * 4);
  float* sint = (float*)alloc((size_t)T_SEQ * 1024 * 4);
  float* h = (float*)alloc((size_t)2048 * 512 * 4);
  bf16* hbf = (bf16*)alloc((size_t)2048 * 512 * 2);
  bf16* hT = (bf16*)alloc((size_t)2048 * 512 * 2);
  bf16* hsp = (bf16*)alloc((size_t)NHEADS * T_SEQ * N_INT * 2);
  bf16* qr = (bf16*)alloc((size_t)NHEADS * T_SEQ * N_INT * 2);   // reused as xy
  bf16* S = (bf16*)alloc((size_t)NHEADS * T_SEQ * T_SEQ * 2);    // reused as dec partials
  bf16* ykv = (bf16*)alloc((size_t)NHEADS * T_SEQ * 512 * 2);
  float* zbuf = (float*)alloc((size_t)2048 * 512 * 4);
  bf16* WoT = (bf16*)alloc((size_t)OUT_PAD * 512 * 2);
  // xbf and WiT alias S (dead until first g_scores)
  bf16* xbf = S;
  bf16* WiT = S + 1048576;

  transpose_cvt<<<dim3(64, 16, 8), dim3(32, 8), 0, stream>>>(enc, encT, 512, N_INT);
  transpose_cvt<<<dim3(64, 16, 8), dim3(32, 8), 0, stream>>>(encv, encvT, 512, N_INT);
  transpose_cvt<<<dim3(16, 512, 1), dim3(32, 8), 0, stream>>>(dec, decT, 16384, 512);
  pad_trans<<<dim3(16, 12), dim3(32, 8), 0, stream>>>(Wi, WiT, IN_DIM, 512, IN_PAD);
  pad_trans<<<dim3(8, 16), dim3(32, 8), 0, stream>>>(Wo, WoT, 512, OUT_DIM, 512);
  cvt_pad_x<<<2048, 256, 0, stream>>>(x, xbf);
  rope_tables<<<1024, 256, 0, stream>>>(cost, sint);
  g_in<<<64, 256, 0, stream>>>(xbf, WiT, bi, zbuf);
  ln0<<<2048, 256, 0, stream>>>(zbuf, h, hbf, hT);

  for (int L = 0; L < 3; ++L) {
    for (int b = 0; b < 2; ++b) {
      const bf16* hbf_b = hbf + (size_t)b * T_SEQ * 512;
      const bf16* hT_b = hT + (size_t)b * 512 * T_SEQ;
      float* zbuf_b = zbuf + (size_t)b * T_SEQ * 512;
      g_hspr<<<1024, 256, 0, stream>>>(hbf_b, encT, cost, sint, hsp, qr);
      g_scores<<<1088, 256, 0, stream>>>(qr, S);
      g_pv<<<1024, 256, 0, stream>>>(S, hT_b, ykv);
      ln_rows<<<8192, 256, 0, stream>>>(ykv);
      g_gate<<<1024, 256, 0, stream>>>(ykv, encvT, hsp, qr);
      g_dec<<<512, 256, 0, stream>>>(qr, decT, S);
      psum16<<<1024, 256, 0, stream>>>(S, zbuf_b);
    }
    ln_double<<<2048, 256, 0, stream>>>(zbuf, h, hbf, hT);
  }
  g_out<<<32, 256, 0, stream>>>(hbf, WoT, bo, out);
}

// Round 9
// 1029.218 us; speedup vs baseline: 1.0246x; 1.0246x over previous
//
#include <hip/hip_runtime.h>

// ---------- types ----------
typedef __bf16 bf16;
typedef __attribute__((ext_vector_type(8))) __bf16 bf16x8;
typedef __attribute__((ext_vector_type(4))) float f32x4;

#define T_SEQ 1024
#define D_MODEL 512
#define N_INT 2048
#define NHEADS 8
#define IN_DIM 372
#define IN_PAD 384
#define OUT_DIM 186
#define OUT_PAD 256

__device__ inline void gld16(const bf16* g, bf16* l) {
  __builtin_amdgcn_global_load_lds((const __attribute__((address_space(1))) void*)g,
                                   (__attribute__((address_space(3))) void*)l, 16, 0, 0);
}

// block-wide sum of two values (256 threads)
__device__ inline void block_sum2(float& a, float& b, float* red) {
#pragma unroll
  for (int o = 32; o > 0; o >>= 1) {
    a += __shfl_down(a, o, 64);
    b += __shfl_down(b, o, 64);
  }
  __syncthreads();
  if ((threadIdx.x & 63) == 0) {
    int w = threadIdx.x >> 6;
    red[2 * w] = a;
    red[2 * w + 1] = b;
  }
  __syncthreads();
  a = red[0] + red[2] + red[4] + red[6];
  b = red[1] + red[3] + red[5] + red[7];
}

// ---------- transpose + fp32->bf16 convert ----------
__global__ __launch_bounds__(256) void transpose_cvt(const float* __restrict__ in,
                                                     bf16* __restrict__ out,
                                                     int rows, int cols) {
  __shared__ float tile[32][33];
  size_t zoff = (size_t)blockIdx.z * rows * cols;
  in += zoff;
  out += zoff;
  int c0 = blockIdx.x * 32, r0 = blockIdx.y * 32;
#pragma unroll
  for (int i = threadIdx.y; i < 32; i += 8)
    tile[i][threadIdx.x] = in[(size_t)(r0 + i) * cols + c0 + threadIdx.x];
  __syncthreads();
#pragma unroll
  for (int i = threadIdx.y; i < 32; i += 8)
    out[(size_t)(c0 + i) * rows + r0 + threadIdx.x] = (bf16)tile[threadIdx.x][i];
}

// ---------- zero-padded transpose + cvt ----------
__global__ __launch_bounds__(256) void pad_trans(const float* __restrict__ in,
                                                 bf16* __restrict__ out,
                                                 int R, int C, int outLd) {
  __shared__ float tile[32][33];
  int c0 = blockIdx.x * 32, r0 = blockIdx.y * 32;
#pragma unroll
  for (int i = threadIdx.y; i < 32; i += 8) {
    int r = r0 + i, c = c0 + threadIdx.x;
    tile[i][threadIdx.x] = (r < R && c < C) ? in[(size_t)r * C + c] : 0.f;
  }
  __syncthreads();
#pragma unroll
  for (int i = threadIdx.y; i < 32; i += 8)
    out[(size_t)(c0 + i) * outLd + r0 + threadIdx.x] = (bf16)tile[threadIdx.x][i];
}

// ---------- x fp32 [2048][372] -> xbf bf16 [2048][384] zero-padded ----------
__global__ __launch_bounds__(256) void cvt_pad_x(const float* __restrict__ x,
                                                 bf16* __restrict__ xbf) {
  size_t r = blockIdx.x;
  for (int c = threadIdx.x; c < IN_PAD; c += 256)
    xbf[r * IN_PAD + c] = (c < IN_DIM) ? (bf16)x[r * IN_DIM + c] : (bf16)0.f;
}

// ---------- RoPE tables ----------
__global__ __launch_bounds__(256) void rope_tables(float* __restrict__ ct, float* __restrict__ st) {
  int t = blockIdx.x;
  for (int i = threadIdx.x; i < 1024; i += 256) {
    float ph = (float)t * exp2f(-16.0f * (float)i * (1.0f / 1024.0f));
    ct[(size_t)t * 1024 + i] = cosf(ph);
    st[(size_t)t * 1024 + i] = sinf(ph);
  }
}

// ---------- sum 16 bf16 split-K partials -> fp32 zbuf (per batch) ----------
__global__ __launch_bounds__(256) void psum16(const bf16* __restrict__ part,
                                              float* __restrict__ zb) {
  size_t r = blockIdx.x;  // 1024 rows
  for (int cc = threadIdx.x; cc < 512; cc += 256) {
    float s = 0.f;
#pragma unroll
    for (int k = 0; k < 16; ++k)
      s += (float)part[((size_t)k << 19) + r * 512 + cc];
    zb[r * 512 + cc] = s;
  }
}

// ---------- ln0: h = LN(z) ----------
__global__ __launch_bounds__(256) void ln0(const float* __restrict__ zin,
                                           float* __restrict__ h, bf16* __restrict__ hbf,
                                           bf16* __restrict__ hT) {
  __shared__ float red[8];
  size_t r = blockIdx.x;
  int tid = threadIdx.x;
  float v0 = zin[r * 512 + tid], v1 = zin[r * 512 + tid + 256];
  float s = v0 + v1, s2 = v0 * v0 + v1 * v1;
  block_sum2(s, s2, red);
  float mean = s * (1.f / 512.f);
  float var = s2 * (1.f / 512.f) - mean * mean;
  float rs = rsqrtf(var + 1e-5f);
  float o0 = (v0 - mean) * rs, o1 = (v1 - mean) * rs;
  h[r * 512 + tid] = o0;
  h[r * 512 + tid + 256] = o1;
  hbf[r * 512 + tid] = (bf16)o0;
  hbf[r * 512 + tid + 256] = (bf16)o1;
  int b = (int)(r >> 10), t = (int)(r & (T_SEQ - 1));
  hT[((size_t)b * 512 + tid) * T_SEQ + t] = (bf16)o0;
  hT[((size_t)b * 512 + tid + 256) * T_SEQ + t] = (bf16)o1;
}

// ---------- wave-per-row in-place LN on bf16 rows of 512 (4 rows/block) ----------
__global__ __launch_bounds__(256) void ln_rows(bf16* __restrict__ io) {
  const int wid = threadIdx.x >> 6, lane = threadIdx.x & 63;
  size_t r = (size_t)blockIdx.x * 4 + wid;
  bf16* p = io + r * 512 + lane * 8;
  bf16x8 v = *(const bf16x8*)p;
  float f[8], s = 0.f, s2 = 0.f;
#pragma unroll
  for (int j = 0; j < 8; ++j) {
    f[j] = (float)v[j];
    s += f[j];
    s2 += f[j] * f[j];
  }
#pragma unroll
  for (int o = 32; o > 0; o >>= 1) {
    s += __shfl_xor(s, o, 64);
    s2 += __shfl_xor(s2, o, 64);
  }
  float mean = s * (1.f / 512.f);
  float var = s2 * (1.f / 512.f) - mean * mean;
  float rs = rsqrtf(var + 1e-5f);
  bf16x8 o;
#pragma unroll
  for (int j = 0; j < 8; ++j) o[j] = (bf16)((f[j] - mean) * rs);
  *(bf16x8*)p = o;
}

// ---------- h = LN(h_res + LN(z)) ----------
__global__ __launch_bounds__(256) void ln_double(const float* __restrict__ zin,
                                                 float* __restrict__ h, bf16* __restrict__ hbf,
                                                 bf16* __restrict__ hT) {
  __shared__ float red[8];
  size_t r = blockIdx.x;
  int tid = threadIdx.x;
  float z0 = zin[r * 512 + tid], z1 = zin[r * 512 + tid + 256];
  float s = z0 + z1, s2 = z0 * z0 + z1 * z1;
  block_sum2(s, s2, red);
  float m1 = s * (1.f / 512.f);
  float v1_ = s2 * (1.f / 512.f) - m1 * m1;
  float rs1 = rsqrtf(v1_ + 1e-5f);
  float a0 = (z0 - m1) * rs1 + h[r * 512 + tid];
  float a1 = (z1 - m1) * rs1 + h[r * 512 + tid + 256];
  s = a0 + a1;
  s2 = a0 * a0 + a1 * a1;
  block_sum2(s, s2, red);
  float m2 = s * (1.f / 512.f);
  float v2_ = s2 * (1.f / 512.f) - m2 * m2;
  float rs2 = rsqrtf(v2_ + 1e-5f);
  float o0 = (a0 - m2) * rs2, o1 = (a1 - m2) * rs2;
  h[r * 512 + tid] = o0;
  h[r * 512 + tid + 256] = o1;
  hbf[r * 512 + tid] = (bf16)o0;
  hbf[r * 512 + tid + 256] = (bf16)o1;
  int b = (int)(r >> 10), t = (int)(r & (T_SEQ - 1));
  hT[((size_t)b * 512 + tid) * T_SEQ + t] = (bf16)o0;
  hT[((size_t)b * 512 + tid + 256) * T_SEQ + t] = (bf16)o1;
}

// ---------- fused hsp+RoPE GEMM (correct single-barrier T3 2-phase loop) ----------
// per iter: {stage NEXT into buf^1} -> {compute buf} -> {vmcnt(0) + barrier}
__global__ __launch_bounds__(256, 2) void g_hspr(const bf16* __restrict__ hbf_b,
                                                 const bf16* __restrict__ encT,
                                                 const float* __restrict__ ct,
                                                 const float* __restrict__ st,
                                                 bf16* __restrict__ hsp,
                                                 bf16* __restrict__ qr) {
  const int id = blockIdx.x;
  const int bz = id & 7;
  const int r_ = id >> 3;
  const int bi = r_ & 7;
  const int bj = r_ >> 3;

  const bf16* B0 = encT + (size_t)bz * N_INT * 512 + (size_t)(bj * 64) * 512;
  const bf16* B1 = B0 + (size_t)1024 * 512;

  const int tid = threadIdx.x;
  const int trow = tid >> 3, tq = tid & 7;
  const int sq = tq ^ (trow & 7);
  const bf16* ags = hbf_b + (size_t)(bi * 128 + trow) * 512 + sq * 8;
  const bf16* bgs0 = B0 + (size_t)trow * 512 + sq * 8;
  const bf16* bgs1 = B1 + (size_t)trow * 512 + sq * 8;

  __shared__ __align__(16) bf16 As[2][128 * 64];
  __shared__ __align__(16) bf16 Bs[2][2 * 64 * 64];
  const int so = tid * 8;

  const int lane = tid & 63, wid = tid >> 6;
  const int wr = wid >> 1, wc = wid & 1;
  const int fr = lane & 15, fg = lane >> 4;
  const int axor = fr & 7;

  f32x4 acc[4][2][2] = {};

  auto stage = [&](int buf, int kk) {
#pragma unroll
    for (int p = 0; p < 4; ++p)
      gld16(ags + (size_t)(p * 32) * 512 + kk, &As[buf][p * 2048 + so]);
    gld16(bgs0 + kk, &Bs[buf][0 * 2048 + so]);
    gld16(bgs0 + (size_t)32 * 512 + kk, &Bs[buf][1 * 2048 + so]);
    gld16(bgs1 + kk, &Bs[buf][2 * 2048 + so]);
    gld16(bgs1 + (size_t)32 * 512 + kk, &Bs[buf][3 * 2048 + so]);
  };

  // prologue: tile 0 resident
  stage(0, 0);
  asm volatile("s_waitcnt vmcnt(0)" ::: "memory");
  __builtin_amdgcn_s_barrier();

  for (int t = 0; t < 8; ++t) {
    const int cur = t & 1;
    if (t + 1 < 8) stage(cur ^ 1, (t + 1) << 6);  // issue next; latency hides under MFMA

    __builtin_amdgcn_s_setprio(1);
#pragma unroll
    for (int s = 0; s < 2; ++s) {
      bf16x8 af[4], bfv[2][2];
#pragma unroll
      for (int m = 0; m < 4; ++m)
        af[m] = *(const bf16x8*)(&As[cur][(wr * 64 + m * 16 + fr) * 64 + (((s * 4 + fg) ^ axor) * 8)]);
#pragma unroll
      for (int pp = 0; pp < 2; ++pp)
#pragma unroll
        for (int n = 0; n < 2; ++n)
          bfv[pp][n] = *(const bf16x8*)(&Bs[cur][pp * 4096 + (wc * 32 + n * 16 + fr) * 64 + (((s * 4 + fg) ^ axor) * 8)]);
#pragma unroll
      for (int m = 0; m < 4; ++m)
#pragma unroll
        for (int n = 0; n < 2; ++n)
#pragma unroll
          for (int pp = 0; pp < 2; ++pp)
            acc[m][n][pp] = __builtin_amdgcn_mfma_f32_16x16x32_bf16(af[m], bfv[pp][n], acc[m][n][pp], 0, 0, 0);
    }
    __builtin_amdgcn_s_setprio(0);

    // staged writes landed + all waves done reading buf[cur] -> safe to flip
    asm volatile("s_waitcnt vmcnt(0)" ::: "memory");
    __builtin_amdgcn_sched_barrier(0);
    __builtin_amdgcn_s_barrier();
    __builtin_amdgcn_sched_barrier(0);
  }

  const size_t hb = (size_t)bz * T_SEQ;
#pragma unroll
  for (int m = 0; m < 4; ++m) {
#pragma unroll
    for (int n = 0; n < 2; ++n) {
      int c = bj * 64 + wc * 32 + n * 16 + fr;
#pragma unroll
      for (int j = 0; j < 4; ++j) {
        int r = bi * 128 + wr * 64 + m * 16 + fg * 4 + j;
        float v0 = fmaxf(acc[m][n][0][j], 0.f);
        float v1 = fmaxf(acc[m][n][1][j], 0.f);
        float co = ct[(size_t)r * 1024 + c];
        float si = st[(size_t)r * 1024 + c];
        size_t base = (hb + r) * N_INT + c;
        hsp[base] = (bf16)v0;
        hsp[base + 1024] = (bf16)v1;
        qr[base] = (bf16)(v0 * co - v1 * si);
        qr[base + 1024] = (bf16)(v1 * co + v0 * si);
      }
    }
  }
}

// ---------- TILE x TILE bf16 MFMA GEMM body, C = A @ Bt^T ----------
// BK=64, 2-buffer LDS, correct single-barrier T3 2-phase loop:
// {stage NEXT into buf^1} -> {compute buf} -> {vmcnt(0)+barrier}.
// XOR-swizzle (T2, pre-swizzled global source), XCD pin (T1).
template <int MODE, int GX, int TILE>
__device__ __forceinline__ void gemm_body(const bf16* __restrict__ Abase,
                                          const bf16* __restrict__ Bbase,
                                          const bf16* __restrict__ aux,
                                          const float* __restrict__ fbias,
                                          float* __restrict__ fout,
                                          bf16* __restrict__ bout) {
  const int id = blockIdx.x;
  int bz = 0, r_, chunk = 0;
  if constexpr (MODE >= 5) {
    r_ = id;
  } else if constexpr (MODE == 4) {
    r_ = id & 31;
    chunk = id >> 5;
  } else {
    bz = id & 7;
    r_ = id >> 3;
  }
  int bi, bj;
  if constexpr (MODE == 1) {
    int l = r_;
    float f = sqrtf(8.0f * (float)l + 1.0f);
    bi = (int)((f - 1.0f) * 0.5f);
    while ((bi + 1) * (bi + 2) / 2 <= l) ++bi;
    while (bi * (bi + 1) / 2 > l) --bi;
    bj = l - bi * (bi + 1) / 2;
  } else {
    bi = r_ % GX;
    bj = r_ / GX;
  }

  const bf16* A;
  const bf16* Bt;
  int lda, ldb, kend;
  if constexpr (MODE == 1) {
    A = Abase + (size_t)bz * T_SEQ * N_INT; lda = N_INT;
    Bt = A; ldb = N_INT;
    kend = N_INT;
  } else if constexpr (MODE == 2) {
    A = Abase + (size_t)bz * T_SEQ * T_SEQ; lda = T_SEQ;
    Bt = Bbase; ldb = T_SEQ;
    kend = (bi + 1) * TILE;
  } else if constexpr (MODE == 3) {
    A = Abase + (size_t)bz * T_SEQ * 512; lda = 512;
    Bt = Bbase + (size_t)bz * N_INT * 512; ldb = 512;
    kend = 512;
  } else if constexpr (MODE == 4) {
    A = Abase + (size_t)chunk * 1024; lda = 16384;
    Bt = Bbase + (size_t)chunk * 1024; ldb = 16384;
    kend = 1024;
  } else if constexpr (MODE == 5) {
    A = Abase; lda = IN_PAD;
    Bt = Bbase; ldb = IN_PAD;
    kend = IN_PAD;
  } else {
    A = Abase; lda = 512;
    Bt = Bbase; ldb = 512;
    kend = 512;
  }

  const int tid = threadIdx.x;
  constexpr int PASSES = TILE / 32;
  const int trow = tid >> 3, tq = tid & 7;
  const int sq = tq ^ (trow & 7);
  const bf16* ags = A + (size_t)(bi * TILE + trow) * lda + sq * 8;
  const bf16* bgs = Bt + (size_t)(bj * TILE + trow) * ldb + sq * 8;

  __shared__ __align__(16) bf16 As[2][TILE * 64];
  __shared__ __align__(16) bf16 Bs[2][TILE * 64];
  const int so = tid * 8;

  const int lane = tid & 63, wid = tid >> 6;
  const int wr = wid >> 1, wc = wid & 1;
  const int fr = lane & 15, fg = lane >> 4;
  const int axor = fr & 7;
  constexpr int MR = TILE / 32;

  f32x4 acc[MR][MR] = {};

  auto stage = [&](int buf, int kk) {
#pragma unroll
    for (int p = 0; p < PASSES; ++p) {
      gld16(ags + (size_t)(p * 32) * lda + kk, &As[buf][p * 2048 + so]);
      gld16(bgs + (size_t)(p * 32) * ldb + kk, &Bs[buf][p * 2048 + so]);
    }
  };

  const int nt = kend >> 6;
  // prologue: tile 0 resident
  stage(0, 0);
  asm volatile("s_waitcnt vmcnt(0)" ::: "memory");
  __builtin_amdgcn_s_barrier();

  for (int t = 0; t < nt; ++t) {
    const int cur = t & 1;
    if (t + 1 < nt) stage(cur ^ 1, (t + 1) << 6);  // issue next; hides under MFMA

    __builtin_amdgcn_s_setprio(1);
#pragma unroll
    for (int s = 0; s < 2; ++s) {
      bf16x8 af[MR], bfv[MR];
#pragma unroll
      for (int m = 0; m < MR; ++m)
        af[m] = *(const bf16x8*)(&As[cur][(wr * (TILE / 2) + m * 16 + fr) * 64 + (((s * 4 + fg) ^ axor) * 8)]);
#pragma unroll
      for (int n = 0; n < MR; ++n)
        bfv[n] = *(const bf16x8*)(&Bs[cur][(wc * (TILE / 2) + n * 16 + fr) * 64 + (((s * 4 + fg) ^ axor) * 8)]);
#pragma unroll
      for (int m = 0; m < MR; ++m)
#pragma unroll
        for (int n = 0; n < MR; ++n)
          acc[m][n] = __builtin_amdgcn_mfma_f32_16x16x32_bf16(af[m], bfv[n], acc[m][n], 0, 0, 0);
    }
    __builtin_amdgcn_s_setprio(0);

    // staged writes landed + all waves done reading buf[cur] -> safe to flip
    asm volatile("s_waitcnt vmcnt(0)" ::: "memory");
    __builtin_amdgcn_sched_barrier(0);
    __builtin_amdgcn_s_barrier();
    __builtin_amdgcn_sched_barrier(0);
  }

#pragma unroll
  for (int m = 0; m < MR; ++m) {
#pragma unroll
    for (int n = 0; n < MR; ++n) {
#pragma unroll
      for (int j = 0; j < 4; ++j) {
        int r = bi * TILE + wr * (TILE / 2) + m * 16 + fg * 4 + j;
        int c = bj * TILE + wc * (TILE / 2) + n * 16 + fr;
        float v = acc[m][n][j];
        if constexpr (MODE == 1) {
          bout[(size_t)bz * T_SEQ * T_SEQ + (size_t)r * T_SEQ + c] = (bf16)(c < r ? v : 0.f);
        } else if constexpr (MODE == 2) {
          bout[((size_t)bz * T_SEQ + r) * 512 + c] = (bf16)v;
        } else if constexpr (MODE == 3) {
          v = fmaxf(v, 0.f);
          float g = (float)aux[((size_t)bz * T_SEQ + r) * N_INT + c];
          bout[(size_t)r * 16384 + (size_t)bz * N_INT + c] = (bf16)(v * g);
        } else if constexpr (MODE == 4) {
          bout[((size_t)chunk << 19) + (size_t)r * 512 + c] = (bf16)v;
        } else if constexpr (MODE == 5) {
          fout[(size_t)r * 512 + c] = v + fbias[c];
        } else {
          if (c < OUT_DIM) fout[(size_t)r * OUT_DIM + c] = v + fbias[c];
        }
      }
    }
  }
}

// ---------- named wrappers ----------
__global__ __launch_bounds__(256, 4) void g_scores(const bf16* A, bf16* o) {
  gemm_body<1, 0, 64>(A, nullptr, nullptr, nullptr, nullptr, o);
}
__global__ __launch_bounds__(256, 4) void g_pv(const bf16* A, const bf16* B, bf16* o) {
  gemm_body<2, 16, 64>(A, B, nullptr, nullptr, nullptr, o);
}
__global__ __launch_bounds__(256, 2) void g_gate(const bf16* A, const bf16* B, const bf16* aux, bf16* o) {
  gemm_body<3, 8, 128>(A, B, aux, nullptr, nullptr, o);
}
__global__ __launch_bounds__(256, 2) void g_dec(const bf16* A, const bf16* B, bf16* o) {
  gemm_body<4, 8, 128>(A, B, nullptr, nullptr, nullptr, o);
}
__global__ __launch_bounds__(256, 2) void g_in(const bf16* A, const bf16* B, const float* bias, float* o) {
  gemm_body<5, 16, 128>(A, B, nullptr, bias, o, nullptr);
}
__global__ __launch_bounds__(256, 2) void g_out(const bf16* A, const bf16* B, const float* bias, float* o) {
  gemm_body<6, 16, 128>(A, B, nullptr, bias, o, nullptr);
}

// ---------- launch ----------
extern "C" void kernel_launch(void* const* d_in, const int* in_sizes, int n_in,
                              void* d_out, int out_size, void* d_ws, size_t ws_size,
                              hipStream_t stream) {
  const float* x = (const float*)d_in[0];
  const float* Wi = (const float*)d_in[1];
  const float* bi = (const float*)d_in[2];
  const float* enc = (const float*)d_in[3];
  const float* encv = (const float*)d_in[4];
  const float* dec = (const float*)d_in[5];
  const float* Wo = (const float*)d_in[6];
  const float* bo = (const float*)d_in[7];
  float* out = (float*)d_out;

  const size_t NEED = 163840000;
  if (ws_size < NEED) return;

  char* w = (char*)d_ws;
  auto alloc = [&](size_t bytes) {
    char* p = w;
    w += (bytes + 255) & ~(size_t)255;
    return p;
  };
  bf16* encT = (bf16*)alloc((size_t)NHEADS * N_INT * 512 * 2);
  bf16* encvT = (bf16*)alloc((size_t)NHEADS * N_INT * 512 * 2);
  bf16* decT = (bf16*)alloc((size_t)512 * 16384 * 2);
  float* cost = (float*)alloc((size_t)T_SEQ * 1024 * 4);
  float* sint = (float*)alloc((size_t)T_SEQ * 1024 * 4);
  float* h = (float*)alloc((size_t)2048 * 512 * 4);
  bf16* hbf = (bf16*)alloc((size_t)2048 * 512 * 2);
  bf16* hT = (bf16*)alloc((size_t)2048 * 512 * 2);
  bf16* hsp = (bf16*)alloc((size_t)NHEADS * T_SEQ * N_INT * 2);
  bf16* qr = (bf16*)alloc((size_t)NHEADS * T_SEQ * N_INT * 2);   // reused as xy
  bf16* S = (bf16*)alloc((size_t)NHEADS * T_SEQ * T_SEQ * 2);    // reused as dec partials
  bf16* ykv = (bf16*)alloc((size_t)NHEADS * T_SEQ * 512 * 2);
  float* zbuf = (float*)alloc((size_t)2048 * 512 * 4);
  bf16* WoT = (bf16*)alloc((size_t)OUT_PAD * 512 * 2);
  // xbf and WiT alias S (dead until first g_scores)
  bf16* xbf = S;
  bf16* WiT = S + 1048576;

  transpose_cvt<<<dim3(64, 16, 8), dim3(32, 8), 0, stream>>>(enc, encT, 512, N_INT);
  transpose_cvt<<<dim3(64, 16, 8), dim3(32, 8), 0, stream>>>(encv, encvT, 512, N_INT);
  transpose_cvt<<<dim3(16, 512, 1), dim3(32, 8), 0, stream>>>(dec, decT, 16384, 512);
  pad_trans<<<dim3(16, 12), dim3(32, 8), 0, stream>>>(Wi, WiT, IN_DIM, 512, IN_PAD);
  pad_trans<<<dim3(8, 16), dim3(32, 8), 0, stream>>>(Wo, WoT, 512, OUT_DIM, 512);
  cvt_pad_x<<<2048, 256, 0, stream>>>(x, xbf);
  rope_tables<<<1024, 256, 0, stream>>>(cost, sint);
  g_in<<<64, 256, 0, stream>>>(xbf, WiT, bi, zbuf);
  ln0<<<2048, 256, 0, stream>>>(zbuf, h, hbf, hT);

  for (int L = 0; L < 3; ++L) {
    for (int b = 0; b < 2; ++b) {
      const bf16* hbf_b = hbf + (size_t)b * T_SEQ * 512;
      const bf16* hT_b = hT + (size_t)b * 512 * T_SEQ;
      float* zbuf_b = zbuf + (size_t)b * T_SEQ * 512;
      g_hspr<<<1024, 256, 0, stream>>>(hbf_b, encT, cost, sint, hsp, qr);
      g_scores<<<1088, 256, 0, stream>>>(qr, S);
      g_pv<<<1024, 256, 0, stream>>>(S, hT_b, ykv);
      ln_rows<<<2048, 256, 0, stream>>>(ykv);
      g_gate<<<1024, 256, 0, stream>>>(ykv, encvT, hsp, qr);
      g_dec<<<512, 256, 0, stream>>>(qr, decT, S);
      psum16<<<1024, 256, 0, stream>>>(S, zbuf_b);
    }
    ln_double<<<2048, 256, 0, stream>>>(zbuf, h, hbf, hT);
  }
  g_out<<<32, 256, 0, stream>>>(hbf, WoT, bo, out);
}